// Round 3
// baseline (1195.464 us; speedup 1.0000x reference)
//
#include <hip/hip_runtime.h>
#include <hip/hip_bf16.h>
#include <hip/hip_cooperative_groups.h>

namespace cg = cooperative_groups;

// B=4, N=256, F=64, H=256, A=16, T=3.  BN=1024 rows.
// bf16 inputs (runtime-verified); adjacency int32.
// GEMMs: bf16 MFMA 16x16x32. Weights are EXACT in bf16 (inputs are bf16).
// Precision: activations h/Ehat stored as split hi/lo bf16 pairs along K,
// weights duplicated along K -> A_hi@B + A_lo@B in one MFMA GEMM (~fp32 acc).
// R1: agg.gi fused via precomputed Wg = W2hat.Wih (3-term split-K, K=864).
// R2: wg_kernel latency fix (batched loads, 216 blocks).  311us, all
//     dispatches <42us -> orchestration-bound (16 serial dispatches).
// R3: single cooperative megakernel, 15 grid.sync() phases, 1 dispatch.
//     Grid-size-agnostic strided loops; 64x64 GEMM tiles; msg rows
//     XCD-swizzled; detect computed redundantly per-block.

typedef unsigned short ushort_t;
typedef short bf8_t __attribute__((ext_vector_type(8)));
typedef float f4_t  __attribute__((ext_vector_type(4)));

// ---- bf16 regions (USHORT offsets) ----
#define UB_NFB    0         // 65536   NF [1024][64] (exact)
#define UB_PW1T   65536     // 16384   preW1^T [256][64]
#define UB_PW2T   81920     // 65536   preW2^T [256][256]
#define UB_WCATT  147456    // 655360  Wcat^T dup [1280][512]
#define UB_WGT    802816    // 663552  Wg^T [768][864] = [hi(288)|hi(288)|lo(288)]
#define UB_XB     1466368   // 262144  X [1024][256] single bf16
#define UB_H2     1728512   // 524288  h  [1024][512] hi|lo
#define UB_EHAT2  2252800   // 884736  Ehat [1024][864] hi(288)|lo(288)|hi(288)
#define UB_END    3137536   // -> 1568768 floats

// ---- fp32 regions (FLOAT offsets), contiguous from F_PREB1 ----
#define F_PREB1   1568768   // 256
#define F_PREB2   1569024   // 256
#define F_BCAT    1569280   // 1280  [msg_b1 | 0 | gru_bhh]
#define F_BIH     1570560   // 768
#define F_ROW1    1571328   // 65536
#define F_ROB1    1636864   // 256
#define F_ROW2    1637120   // 4096
#define F_ROB2    1641216   // 16
#define F_H       1641232   // 262144
#define F_HCAT    1903376   // 1310720 [hi_p | hj | gh]
#define F_GI      3214096   // 786432

// ---- convert index space ----
#define CVa 65536     // end NFB
#define CVb 81920     // end PW1T
#define CVc 147456    // end PW2T
#define CVd 802816    // end WCATT
#define CV_TOTAL 875280   // + 72464 fp32 tail

__device__ __forceinline__ float bf2f(ushort_t u) {
    return __uint_as_float(((unsigned int)u) << 16);
}
__device__ __forceinline__ ushort_t f2b(float v) {
    __hip_bfloat16 b = __float2bfloat16(v);
    return *reinterpret_cast<ushort_t*>(&b);
}
__device__ __forceinline__ float relu(float v) { return v < 0.f ? 0.f : v; }  // NaN-propagating
__device__ __forceinline__ float ld(const void* p, int i, int isf32) {
    return isf32 ? ((const float*)p)[i] : bf2f(((const ushort_t*)p)[i]);
}

struct MegaArgs {
    const void* P[18];
    float* w;
    void* out;
};

// bf16 MFMA GEMM phase: C[1024,N] = A[1024,K] @ Bt[N,K]^T (+bias)(+relu).
// 64x64 tiles, 4 waves of 32x32, gridDim-strided tile loop.
__device__ void dgemm64(const ushort_t* __restrict__ A,
                        const ushort_t* __restrict__ Bt,
                        const float* __restrict__ bias,
                        float* __restrict__ C,
                        ushort_t* __restrict__ Cb, int cbld, int cblo,
                        int K, int N, int dorelu,
                        int nb, int bid, int t, char* smem)
{
    ushort_t* As = (ushort_t*)smem;            // [64][32]
    ushort_t* Bs = (ushort_t*)smem + 64 * 32;  // [64][32]
    const int wave = t >> 6, lane = t & 63;
    const int ln = lane & 15, quad = lane >> 4;
    const int wm = (wave >> 1) * 32, wn = (wave & 1) * 32;
    const int srow = t >> 2, skc = (t & 3) << 3;
    const int ntiles = (N >> 6) << 4;          // (N/64) * 16 bm-groups

    for (int tile = bid; tile < ntiles; tile += nb) {
        const int bm = (tile & 15) << 6;
        const int bn = (tile >> 4) << 6;
        f4_t acc[2][2] = {};
        for (int k0 = 0; k0 < K; k0 += 32) {
            __syncthreads();
            *(bf8_t*)(&As[srow * 32 + skc]) = *(const bf8_t*)(&A[(bm + srow) * K + k0 + skc]);
            *(bf8_t*)(&Bs[srow * 32 + skc]) = *(const bf8_t*)(&Bt[(bn + srow) * K + k0 + skc]);
            __syncthreads();
            bf8_t af[2], bfr[2];
#pragma unroll
            for (int i = 0; i < 2; ++i) {
                af[i]  = *(const bf8_t*)(&As[(wm + i * 16 + ln) * 32 + quad * 8]);
                bfr[i] = *(const bf8_t*)(&Bs[(wn + i * 16 + ln) * 32 + quad * 8]);
            }
#pragma unroll
            for (int mi = 0; mi < 2; ++mi)
#pragma unroll
                for (int ni = 0; ni < 2; ++ni)
                    acc[mi][ni] = __builtin_amdgcn_mfma_f32_16x16x32_bf16(
                        af[mi], bfr[ni], acc[mi][ni], 0, 0, 0);
        }
#pragma unroll
        for (int mi = 0; mi < 2; ++mi) {
#pragma unroll
            for (int ni = 0; ni < 2; ++ni) {
                int col = bn + wn + ni * 16 + ln;
                float bb = bias ? bias[col] : 0.f;
#pragma unroll
                for (int r = 0; r < 4; ++r) {
                    int row = bm + wm + mi * 16 + quad * 4 + r;
                    float v = acc[mi][ni][r] + bb;
                    if (dorelu) v = relu(v);
                    if (C) C[row * N + col] = v;
                    if (Cb) {
                        ushort_t hi = f2b(v);
                        Cb[row * cbld + col] = hi;
                        if (cblo) Cb[row * cbld + cblo + col] = f2b(v - bf2f(hi));
                    }
                }
            }
        }
    }
}

__global__ __launch_bounds__(256, 2) void mega_kernel(MegaArgs a)
{
    auto grid = cg::this_grid();
    const int nb = gridDim.x, bid = blockIdx.x, t = threadIdx.x;
    float* __restrict__ w = a.w;
    ushort_t* __restrict__ wb = (ushort_t*)w;
    const int* __restrict__ adj = (const int*)a.P[1];

    __shared__ __align__(16) char smem[8704];   // 8KB GEMM tiles + tail scalars
    int* cntp = (int*)(smem + 8192);

    // ---- phase 0a: detect (redundant per-block, deterministic) ----
    {
        const ushort_t* nf0 = (const ushort_t*)a.P[0];
        if (t == 0) *cntp = 0;
        __syncthreads();
        int bad = 0;
        for (int i = 0; i < 8; ++i) {
            ushort_t u = nf0[(t * 8 + i) * 2];
            int ex = (u >> 7) & 0xFF;
            if ((u & 0x7fff) != 0 && (ex < 100 || ex > 140)) bad++;
        }
        atomicAdd(cntp, bad);
        __syncthreads();
    }
    const int f32 = (*cntp > 512) ? 1 : 0;
    __syncthreads();

    // ---- phase 0b: convert (all blocks) -- independent of wg below ----
    for (int e = bid * 256 + t; e < CV_TOTAL; e += nb * 256) {
        if (e < CVa) {                                    // NF
            wb[UB_NFB + e] = f2b(ld(a.P[0], e, f32));
        } else if (e < CVb) {                             // preW1^T [256][64]
            int i = e - CVa; int n = i >> 6, k = i & 63;
            wb[UB_PW1T + i] = f2b(ld(a.P[2], k * 256 + n, f32));
        } else if (e < CVc) {                             // preW2^T [256][256]
            int i = e - CVb; int n = i >> 8, k = i & 255;
            wb[UB_PW2T + i] = f2b(ld(a.P[4], k * 256 + n, f32));
        } else if (e < CVd) {                             // Wcat^T dup [1280][512]
            int i = e - CVc; int n = i >> 9, k = (i & 511) & 255;
            float v;
            if (n < 256)      v = ld(a.P[6], k * 256 + n, f32);
            else if (n < 512) v = ld(a.P[6], (256 + k) * 256 + (n - 256), f32);
            else              v = ld(a.P[11], k * 768 + (n - 512), f32);
            wb[UB_WCATT + i] = f2b(v);
        } else {                                          // fp32 tail (contiguous)
            int f = e - CVd;
            float v;
            if (f < 256)        v = ld(a.P[3], f, f32);
            else if (f < 512)   v = ld(a.P[5], f - 256, f32);
            else if (f < 1792) {
                int c = f - 512;
                if (c < 256)      v = ld(a.P[7], c, f32);
                else if (c < 512) v = 0.f;
                else              v = ld(a.P[13], c - 512, f32);
            }
            else if (f < 2560)  v = ld(a.P[12], f - 1792, f32);
            else if (f < 68096) v = ld(a.P[14], f - 2560, f32);
            else if (f < 68352) v = ld(a.P[15], f - 68096, f32);
            else if (f < 72448) v = ld(a.P[16], f - 68352, f32);
            else                v = ld(a.P[17], f - 72448, f32);
            w[F_PREB1 + f] = v;
        }
    }

    // ---- phase 0c: Wg = W2hat . Wih (216 tiles; reads only raw inputs,
    //      writes only UB_WGT -> no hazard vs convert, same phase) ----
    {
        float* w2s = (float*)smem;   // 4KB
        for (int wt = bid; wt < 216; wt += nb) {
            int p0 = (wt % 3) * 256;
            int k0 = (wt / 3) * 4;
            __syncthreads();
            for (int i = t; i < 4 * 256; i += 256) {
                int r = i >> 8, n = i & 255;
                int krow = k0 + r;
                float v;
                if (krow < 256)       v = ld(a.P[8], krow * 256 + n, f32);
                else if (krow == 256) v = ld(a.P[9], n, f32);
                else                  v = 0.f;
                w2s[i] = v;
            }
            __syncthreads();
            const int p = p0 + t;
            float acc4[4] = {};
            for (int n0 = 0; n0 < 256; n0 += 32) {
                float wv[32];
#pragma unroll
                for (int i = 0; i < 32; ++i)
                    wv[i] = ld(a.P[10], (n0 + i) * 768 + p, f32);
#pragma unroll
                for (int r = 0; r < 4; ++r) {
                    float acc = acc4[r];
#pragma unroll
                    for (int q = 0; q < 8; ++q) {
                        f4_t w4 = *(const f4_t*)&w2s[r * 256 + n0 + q * 4];
                        acc += w4[0] * wv[q * 4 + 0] + w4[1] * wv[q * 4 + 1]
                             + w4[2] * wv[q * 4 + 2] + w4[3] * wv[q * 4 + 3];
                    }
                    acc4[r] = acc;
                }
            }
#pragma unroll
            for (int r = 0; r < 4; ++r) {
                int krow = k0 + r;
                ushort_t hi = f2b(acc4[r]);
                ushort_t lo = f2b(acc4[r] - bf2f(hi));
                wb[UB_WGT + p * 864 + krow] = hi;
                wb[UB_WGT + p * 864 + 288 + krow] = hi;
                wb[UB_WGT + p * 864 + 576 + krow] = lo;
            }
        }
    }
    grid.sync();

    // ---- pre-net ----
    dgemm64(wb + UB_NFB, wb + UB_PW1T, w + F_PREB1, (float*)nullptr,
            wb + UB_XB, 256, 0, 64, 256, 1, nb, bid, t, smem);
    grid.sync();
    dgemm64(wb + UB_XB, wb + UB_PW2T, w + F_PREB2, w + F_H,
            wb + UB_H2, 512, 256, 256, 256, 0, nb, bid, t, smem);
    grid.sync();

    // ---- T = 3 message-passing iterations ----
    for (int it = 0; it < 3; ++it) {
        // hcat = h @ [W1_i|W1_j|Whh] + [b1|0|bhh]   (A = h hi|lo, K=512)
        dgemm64(wb + UB_H2, wb + UB_WCATT, w + F_BCAT, w + F_HCAT,
                (ushort_t*)nullptr, 0, 0, 512, 1280, 0, nb, bid, t, smem);
        grid.sync();

        // msg: Ehat rows, XCD-swizzled (block's rows stay in one 128-row window)
        {
            int* ej = (int*)smem;          // 1KB
            const float* hcat = w + F_HCAT;
            for (int idx = bid; idx < 1024; idx += nb) {
                const int row = ((idx & 7) << 7) + (idx >> 3);
                __syncthreads();
                if (t == 0) *cntp = 0;
                __syncthreads();
                if (adj[row * 256 + t]) { int p = atomicAdd(cntp, 1); ej[p] = t; }
                const float hi = hcat[row * 1280 + t];
                const float* hjb = hcat + (row >> 8) * (256 * 1280) + 256;
                __syncthreads();
                const int ne = *cntp;
                float acc = 0.f;
#pragma unroll 4
                for (int p = 0; p < ne; ++p) {
                    int j = ej[p];
                    acc += relu(hi + hjb[j * 1280 + t]);
                }
                ushort_t h16 = f2b(acc);
                ushort_t l16 = f2b(acc - bf2f(h16));
                ushort_t* er = wb + UB_EHAT2 + row * 864;
                er[t] = h16;
                er[288 + t] = l16;
                er[576 + t] = h16;
                if (t < 32) {
                    ushort_t d = f2b(t == 0 ? (float)ne : 0.f);  // deg exact (<=256)
                    er[256 + t] = d;
                    er[544 + t] = 0;
                    er[832 + t] = d;
                }
            }
        }
        grid.sync();

        // gi = Ehat @ Wg + bih  (A = Ehat [Eh|El|Eh], K=864; deg col folds msg_b2)
        dgemm64(wb + UB_EHAT2, wb + UB_WGT, w + F_BIH, w + F_GI,
                (ushort_t*)nullptr, 0, 0, 864, 768, 0, nb, bid, t, smem);
        grid.sync();

        // gru
        for (int row = bid; row < 1024; row += nb) {
            const float* gir = w + F_GI + row * 768;
            const float* ghr = w + F_HCAT + row * 1280 + 512;
            float ir = gir[t], iz = gir[256 + t], in = gir[512 + t];
            float hr = ghr[t], hz = ghr[256 + t], hn = ghr[512 + t];
            float r = 1.f / (1.f + __expf(-(ir + hr)));
            float z = 1.f / (1.f + __expf(-(iz + hz)));
            float n = tanhf(in + r * hn);
            float ho = w[F_H + row * 256 + t];
            float hv = (1.f - z) * n + z * ho;
            w[F_H + row * 256 + t] = hv;
            ushort_t hb = f2b(hv);
            wb[UB_H2 + row * 512 + t] = hb;
            wb[UB_H2 + row * 512 + 256 + t] = f2b(hv - bf2f(hb));
        }
        grid.sync();
    }

    // ---- readout (blocks 0..3), no further grid syncs ----
    if (bid < 4) {
        float* gl = (float*)smem;
        float* t1 = gl + 256;
        const float* hb = w + F_H + bid * 256 * 256;
        __syncthreads();
        float s = 0.f;
        for (int n = 0; n < 256; ++n) s += hb[n * 256 + t];
        gl[t] = s;
        __syncthreads();
        float acc = w[F_ROB1 + t];
        for (int k = 0; k < 256; ++k) acc += gl[k] * w[F_ROW1 + k * 256 + t];
        t1[t] = relu(acc);
        __syncthreads();
        if (t < 16) {
            float q = w[F_ROB2 + t];
            for (int k = 0; k < 256; ++k) q += t1[k] * w[F_ROW2 + k * 16 + t];
            if (f32) ((float*)a.out)[bid * 16 + t] = q;
            else ((__hip_bfloat16*)a.out)[bid * 16 + t] = __float2bfloat16(q);
        }
    }
}

extern "C" void kernel_launch(void* const* d_in, const int* in_sizes, int n_in,
                              void* d_out, int out_size, void* d_ws, size_t ws_size,
                              hipStream_t stream) {
    float* w = (float*)d_ws;

    static const int dictSz[18]  = {65536,262144,16384,256,65536,256,131072,256,65536,256,
                                    196608,196608,768,768,65536,256,4096,16};
    static const int alphaSz[18] = {262144,196608,196608,768,768,131072,65536,256,256,
                                    65536,16384,65536,256,256,65536,4096,256,16};
    static const int alphaPos[18] = {9,0,10,12,11,13,5,7,6,8,2,1,4,3,14,16,15,17};
    bool dictOK = true, alphaOK = true;
    for (int i = 0; i < 18 && i < n_in; ++i) {
        if (in_sizes[i] != dictSz[i])  dictOK = false;
        if (in_sizes[i] != alphaSz[i]) alphaOK = false;
    }
    MegaArgs margs;
    for (int l = 0; l < 18; ++l)
        margs.P[l] = d_in[(!dictOK && alphaOK) ? alphaPos[l] : l];
    margs.w = w;
    margs.out = d_out;

    int nbpc = 0;
    hipOccupancyMaxActiveBlocksPerMultiprocessor(&nbpc, mega_kernel, 256, 0);
    int grid = (nbpc >= 2) ? 512 : 256;

    void* kargs[] = { (void*)&margs };
    hipLaunchCooperativeKernel((const void*)mega_kernel, dim3(grid), dim3(256),
                               kargs, 0, stream);
}

// Round 4
// 640.618 us; speedup vs baseline: 1.8661x; 1.8661x over previous
//
#include <hip/hip_runtime.h>
#include <hip/hip_bf16.h>

// B=4, N=256, F=64, H=256, A=16, T=3.  BN=1024 rows.
// bf16 inputs (runtime-verified); adjacency int32.
// GEMMs: bf16 MFMA 16x16x32. Weights are EXACT in bf16 (inputs are bf16).
// Precision: activations h/Ehat stored as split hi/lo bf16 pairs along K,
// weights duplicated along K -> A_hi@B + A_lo@B in one MFMA GEMM (~fp32 acc).
// R1: agg.gi fused via precomputed Wg = W2hat.Wih (3-term split-K, K=864).
// R2: wg_kernel latency fix.  311us, orchestration-bound (16 dispatches).
// R3: cooperative megakernel with cg::grid.sync -> 1195us REGRESSION.
//     PMC: VALUBusy 2.9%x1086us ~= 31us real work; ~900us in 15 grid.sync
//     (~60-70us each; __ockl_grid_sync s_sleep backoff + cache maintenance).
// R4: same structure, hand-rolled barrier: 8 spread sub-counters (128B apart)
//     + block-0 aggregator + generation flag; agent-scope atomic loads with
//     s_sleep(2) backoff; __threadfence release/acquire. Init via 4KB
//     hipMemsetAsync (graph-capture-legal).

typedef unsigned short ushort_t;
typedef short bf8_t __attribute__((ext_vector_type(8)));
typedef float f4_t  __attribute__((ext_vector_type(4)));

// ---- bf16 regions (USHORT offsets) ----
#define UB_NFB    0         // 65536   NF [1024][64] (exact)
#define UB_PW1T   65536     // 16384   preW1^T [256][64]
#define UB_PW2T   81920     // 65536   preW2^T [256][256]
#define UB_WCATT  147456    // 655360  Wcat^T dup [1280][512]
#define UB_WGT    802816    // 663552  Wg^T [768][864] = [hi(288)|hi(288)|lo(288)]
#define UB_XB     1466368   // 262144  X [1024][256] single bf16
#define UB_H2     1728512   // 524288  h  [1024][512] hi|lo
#define UB_EHAT2  2252800   // 884736  Ehat [1024][864] hi(288)|lo(288)|hi(288)
#define UB_END    3137536   // -> 1568768 floats

// ---- fp32 regions (FLOAT offsets), contiguous from F_PREB1 ----
#define F_PREB1   1568768   // 256
#define F_PREB2   1569024   // 256
#define F_BCAT    1569280   // 1280  [msg_b1 | 0 | gru_bhh]
#define F_BIH     1570560   // 768
#define F_ROW1    1571328   // 65536
#define F_ROB1    1636864   // 256
#define F_ROW2    1637120   // 4096
#define F_ROB2    1641216   // 16
#define F_H       1641232   // 262144
#define F_HCAT    1903376   // 1310720 [hi_p | hj | gh]
#define F_GI      3214096   // 786432
#define F_BAR     4000528   // 1024 floats: barrier counters (memset to 0)

// ---- convert index space ----
#define CVa 65536     // end NFB
#define CVb 81920     // end PW1T
#define CVc 147456    // end PW2T
#define CVd 802816    // end WCATT
#define CV_TOTAL 875280   // + 72464 fp32 tail

__device__ __forceinline__ float bf2f(ushort_t u) {
    return __uint_as_float(((unsigned int)u) << 16);
}
__device__ __forceinline__ ushort_t f2b(float v) {
    __hip_bfloat16 b = __float2bfloat16(v);
    return *reinterpret_cast<ushort_t*>(&b);
}
__device__ __forceinline__ float relu(float v) { return v < 0.f ? 0.f : v; }  // NaN-propagating
__device__ __forceinline__ float ld(const void* p, int i, int isf32) {
    return isf32 ? ((const float*)p)[i] : bf2f(((const ushort_t*)p)[i]);
}

// ---- hand-rolled grid barrier ----
// bars[i*32], i<8 : arrival sub-counters (128B apart; block bid -> bid&7)
// bars[512]       : generation flag (own cacheline)
// Monotonic counters; barrier #it complete when sum(sub) == it*nb.
__device__ __forceinline__ void gbar(unsigned* bars, int nb, int bid, unsigned it)
{
    __syncthreads();
    if (threadIdx.x == 0) {
        __threadfence();                                   // release our writes
        atomicAdd(&bars[(bid & 7) * 32], 1u);
        if (bid == 0) {
            unsigned tot;
            do {
                tot = 0;
#pragma unroll
                for (int i = 0; i < 8; ++i)
                    tot += __hip_atomic_load(&bars[i * 32], __ATOMIC_RELAXED,
                                             __HIP_MEMORY_SCOPE_AGENT);
                if (tot < it * (unsigned)nb) __builtin_amdgcn_s_sleep(1);
            } while (tot < it * (unsigned)nb);
            __threadfence();
            __hip_atomic_store(&bars[512], it, __ATOMIC_RELAXED,
                               __HIP_MEMORY_SCOPE_AGENT);
        } else {
            while (__hip_atomic_load(&bars[512], __ATOMIC_RELAXED,
                                     __HIP_MEMORY_SCOPE_AGENT) < it)
                __builtin_amdgcn_s_sleep(2);
        }
        __threadfence();                                   // acquire
    }
    __syncthreads();
}

struct MegaArgs {
    const void* P[18];
    float* w;
    void* out;
};

// bf16 MFMA GEMM phase: C[1024,N] = A[1024,K] @ Bt[N,K]^T (+bias)(+relu).
// 64x64 tiles, 4 waves of 32x32, gridDim-strided tile loop.
__device__ void dgemm64(const ushort_t* __restrict__ A,
                        const ushort_t* __restrict__ Bt,
                        const float* __restrict__ bias,
                        float* __restrict__ C,
                        ushort_t* __restrict__ Cb, int cbld, int cblo,
                        int K, int N, int dorelu,
                        int nb, int bid, int t, char* smem)
{
    ushort_t* As = (ushort_t*)smem;            // [64][32]
    ushort_t* Bs = (ushort_t*)smem + 64 * 32;  // [64][32]
    const int wave = t >> 6, lane = t & 63;
    const int ln = lane & 15, quad = lane >> 4;
    const int wm = (wave >> 1) * 32, wn = (wave & 1) * 32;
    const int srow = t >> 2, skc = (t & 3) << 3;
    const int ntiles = (N >> 6) << 4;          // (N/64) * 16 bm-groups

    for (int tile = bid; tile < ntiles; tile += nb) {
        const int bm = (tile & 15) << 6;
        const int bn = (tile >> 4) << 6;
        f4_t acc[2][2] = {};
        for (int k0 = 0; k0 < K; k0 += 32) {
            __syncthreads();
            *(bf8_t*)(&As[srow * 32 + skc]) = *(const bf8_t*)(&A[(bm + srow) * K + k0 + skc]);
            *(bf8_t*)(&Bs[srow * 32 + skc]) = *(const bf8_t*)(&Bt[(bn + srow) * K + k0 + skc]);
            __syncthreads();
            bf8_t af[2], bfr[2];
#pragma unroll
            for (int i = 0; i < 2; ++i) {
                af[i]  = *(const bf8_t*)(&As[(wm + i * 16 + ln) * 32 + quad * 8]);
                bfr[i] = *(const bf8_t*)(&Bs[(wn + i * 16 + ln) * 32 + quad * 8]);
            }
#pragma unroll
            for (int mi = 0; mi < 2; ++mi)
#pragma unroll
                for (int ni = 0; ni < 2; ++ni)
                    acc[mi][ni] = __builtin_amdgcn_mfma_f32_16x16x32_bf16(
                        af[mi], bfr[ni], acc[mi][ni], 0, 0, 0);
        }
#pragma unroll
        for (int mi = 0; mi < 2; ++mi) {
#pragma unroll
            for (int ni = 0; ni < 2; ++ni) {
                int col = bn + wn + ni * 16 + ln;
                float bb = bias ? bias[col] : 0.f;
#pragma unroll
                for (int r = 0; r < 4; ++r) {
                    int row = bm + wm + mi * 16 + quad * 4 + r;
                    float v = acc[mi][ni][r] + bb;
                    if (dorelu) v = relu(v);
                    if (C) C[row * N + col] = v;
                    if (Cb) {
                        ushort_t hi = f2b(v);
                        Cb[row * cbld + col] = hi;
                        if (cblo) Cb[row * cbld + cblo + col] = f2b(v - bf2f(hi));
                    }
                }
            }
        }
    }
}

__global__ __launch_bounds__(256, 2) void mega_kernel(MegaArgs a)
{
    const int nb = gridDim.x, bid = blockIdx.x, t = threadIdx.x;
    float* __restrict__ w = a.w;
    ushort_t* __restrict__ wb = (ushort_t*)w;
    const int* __restrict__ adj = (const int*)a.P[1];
    unsigned* bars = (unsigned*)(w + F_BAR);
    unsigned bcount = 0;

    __shared__ __align__(16) char smem[8704];   // 8KB GEMM tiles + tail scalars
    int* cntp = (int*)(smem + 8192);

    // ---- phase 0a: detect (redundant per-block, deterministic) ----
    {
        const ushort_t* nf0 = (const ushort_t*)a.P[0];
        if (t == 0) *cntp = 0;
        __syncthreads();
        int bad = 0;
        for (int i = 0; i < 8; ++i) {
            ushort_t u = nf0[(t * 8 + i) * 2];
            int ex = (u >> 7) & 0xFF;
            if ((u & 0x7fff) != 0 && (ex < 100 || ex > 140)) bad++;
        }
        atomicAdd(cntp, bad);
        __syncthreads();
    }
    const int f32 = (*cntp > 512) ? 1 : 0;
    __syncthreads();

    // ---- phase 0b: convert (all blocks) -- independent of wg below ----
    for (int e = bid * 256 + t; e < CV_TOTAL; e += nb * 256) {
        if (e < CVa) {                                    // NF
            wb[UB_NFB + e] = f2b(ld(a.P[0], e, f32));
        } else if (e < CVb) {                             // preW1^T [256][64]
            int i = e - CVa; int n = i >> 6, k = i & 63;
            wb[UB_PW1T + i] = f2b(ld(a.P[2], k * 256 + n, f32));
        } else if (e < CVc) {                             // preW2^T [256][256]
            int i = e - CVb; int n = i >> 8, k = i & 255;
            wb[UB_PW2T + i] = f2b(ld(a.P[4], k * 256 + n, f32));
        } else if (e < CVd) {                             // Wcat^T dup [1280][512]
            int i = e - CVc; int n = i >> 9, k = (i & 511) & 255;
            float v;
            if (n < 256)      v = ld(a.P[6], k * 256 + n, f32);
            else if (n < 512) v = ld(a.P[6], (256 + k) * 256 + (n - 256), f32);
            else              v = ld(a.P[11], k * 768 + (n - 512), f32);
            wb[UB_WCATT + i] = f2b(v);
        } else {                                          // fp32 tail (contiguous)
            int f = e - CVd;
            float v;
            if (f < 256)        v = ld(a.P[3], f, f32);
            else if (f < 512)   v = ld(a.P[5], f - 256, f32);
            else if (f < 1792) {
                int c = f - 512;
                if (c < 256)      v = ld(a.P[7], c, f32);
                else if (c < 512) v = 0.f;
                else              v = ld(a.P[13], c - 512, f32);
            }
            else if (f < 2560)  v = ld(a.P[12], f - 1792, f32);
            else if (f < 68096) v = ld(a.P[14], f - 2560, f32);
            else if (f < 68352) v = ld(a.P[15], f - 68096, f32);
            else if (f < 72448) v = ld(a.P[16], f - 68352, f32);
            else                v = ld(a.P[17], f - 72448, f32);
            w[F_PREB1 + f] = v;
        }
    }

    // ---- phase 0c: Wg = W2hat . Wih (216 tiles; reads only raw inputs,
    //      writes only UB_WGT -> no hazard vs convert, same phase) ----
    {
        float* w2s = (float*)smem;   // 4KB
        for (int wt = bid; wt < 216; wt += nb) {
            int p0 = (wt % 3) * 256;
            int k0 = (wt / 3) * 4;
            __syncthreads();
            for (int i = t; i < 4 * 256; i += 256) {
                int r = i >> 8, n = i & 255;
                int krow = k0 + r;
                float v;
                if (krow < 256)       v = ld(a.P[8], krow * 256 + n, f32);
                else if (krow == 256) v = ld(a.P[9], n, f32);
                else                  v = 0.f;
                w2s[i] = v;
            }
            __syncthreads();
            const int p = p0 + t;
            float acc4[4] = {};
            for (int n0 = 0; n0 < 256; n0 += 32) {
                float wv[32];
#pragma unroll
                for (int i = 0; i < 32; ++i)
                    wv[i] = ld(a.P[10], (n0 + i) * 768 + p, f32);
#pragma unroll
                for (int r = 0; r < 4; ++r) {
                    float acc = acc4[r];
#pragma unroll
                    for (int q = 0; q < 8; ++q) {
                        f4_t w4 = *(const f4_t*)&w2s[r * 256 + n0 + q * 4];
                        acc += w4[0] * wv[q * 4 + 0] + w4[1] * wv[q * 4 + 1]
                             + w4[2] * wv[q * 4 + 2] + w4[3] * wv[q * 4 + 3];
                    }
                    acc4[r] = acc;
                }
            }
#pragma unroll
            for (int r = 0; r < 4; ++r) {
                int krow = k0 + r;
                ushort_t hi = f2b(acc4[r]);
                ushort_t lo = f2b(acc4[r] - bf2f(hi));
                wb[UB_WGT + p * 864 + krow] = hi;
                wb[UB_WGT + p * 864 + 288 + krow] = hi;
                wb[UB_WGT + p * 864 + 576 + krow] = lo;
            }
        }
    }
    gbar(bars, nb, bid, ++bcount);

    // ---- pre-net ----
    dgemm64(wb + UB_NFB, wb + UB_PW1T, w + F_PREB1, (float*)nullptr,
            wb + UB_XB, 256, 0, 64, 256, 1, nb, bid, t, smem);
    gbar(bars, nb, bid, ++bcount);
    dgemm64(wb + UB_XB, wb + UB_PW2T, w + F_PREB2, w + F_H,
            wb + UB_H2, 512, 256, 256, 256, 0, nb, bid, t, smem);
    gbar(bars, nb, bid, ++bcount);

    // ---- T = 3 message-passing iterations ----
    for (int it = 0; it < 3; ++it) {
        // hcat = h @ [W1_i|W1_j|Whh] + [b1|0|bhh]   (A = h hi|lo, K=512)
        dgemm64(wb + UB_H2, wb + UB_WCATT, w + F_BCAT, w + F_HCAT,
                (ushort_t*)nullptr, 0, 0, 512, 1280, 0, nb, bid, t, smem);
        gbar(bars, nb, bid, ++bcount);

        // msg: Ehat rows, XCD-swizzled (block's rows stay in one 128-row window)
        {
            int* ej = (int*)smem;          // 1KB
            const float* hcat = w + F_HCAT;
            for (int idx = bid; idx < 1024; idx += nb) {
                const int row = ((idx & 7) << 7) + (idx >> 3);
                __syncthreads();
                if (t == 0) *cntp = 0;
                __syncthreads();
                if (adj[row * 256 + t]) { int p = atomicAdd(cntp, 1); ej[p] = t; }
                const float hi = hcat[row * 1280 + t];
                const float* hjb = hcat + (row >> 8) * (256 * 1280) + 256;
                __syncthreads();
                const int ne = *cntp;
                float acc = 0.f;
#pragma unroll 4
                for (int p = 0; p < ne; ++p) {
                    int j = ej[p];
                    acc += relu(hi + hjb[j * 1280 + t]);
                }
                ushort_t h16 = f2b(acc);
                ushort_t l16 = f2b(acc - bf2f(h16));
                ushort_t* er = wb + UB_EHAT2 + row * 864;
                er[t] = h16;
                er[288 + t] = l16;
                er[576 + t] = h16;
                if (t < 32) {
                    ushort_t d = f2b(t == 0 ? (float)ne : 0.f);  // deg exact (<=256)
                    er[256 + t] = d;
                    er[544 + t] = 0;
                    er[832 + t] = d;
                }
            }
        }
        gbar(bars, nb, bid, ++bcount);

        // gi = Ehat @ Wg + bih  (A = Ehat [Eh|El|Eh], K=864; deg col folds msg_b2)
        dgemm64(wb + UB_EHAT2, wb + UB_WGT, w + F_BIH, w + F_GI,
                (ushort_t*)nullptr, 0, 0, 864, 768, 0, nb, bid, t, smem);
        gbar(bars, nb, bid, ++bcount);

        // gru
        for (int row = bid; row < 1024; row += nb) {
            const float* gir = w + F_GI + row * 768;
            const float* ghr = w + F_HCAT + row * 1280 + 512;
            float ir = gir[t], iz = gir[256 + t], in = gir[512 + t];
            float hr = ghr[t], hz = ghr[256 + t], hn = ghr[512 + t];
            float r = 1.f / (1.f + __expf(-(ir + hr)));
            float z = 1.f / (1.f + __expf(-(iz + hz)));
            float n = tanhf(in + r * hn);
            float ho = w[F_H + row * 256 + t];
            float hv = (1.f - z) * n + z * ho;
            w[F_H + row * 256 + t] = hv;
            ushort_t hb = f2b(hv);
            wb[UB_H2 + row * 512 + t] = hb;
            wb[UB_H2 + row * 512 + 256 + t] = f2b(hv - bf2f(hb));
        }
        gbar(bars, nb, bid, ++bcount);
    }

    // ---- readout (blocks 0..3), no further grid syncs ----
    if (bid < 4) {
        float* gl = (float*)smem;
        float* t1 = gl + 256;
        const float* hb = w + F_H + bid * 256 * 256;
        __syncthreads();
        float s = 0.f;
        for (int n = 0; n < 256; ++n) s += hb[n * 256 + t];
        gl[t] = s;
        __syncthreads();
        float acc = w[F_ROB1 + t];
        for (int k = 0; k < 256; ++k) acc += gl[k] * w[F_ROW1 + k * 256 + t];
        t1[t] = relu(acc);
        __syncthreads();
        if (t < 16) {
            float q = w[F_ROB2 + t];
            for (int k = 0; k < 256; ++k) q += t1[k] * w[F_ROW2 + k * 16 + t];
            if (f32) ((float*)a.out)[bid * 16 + t] = q;
            else ((__hip_bfloat16*)a.out)[bid * 16 + t] = __float2bfloat16(q);
        }
    }
}

extern "C" void kernel_launch(void* const* d_in, const int* in_sizes, int n_in,
                              void* d_out, int out_size, void* d_ws, size_t ws_size,
                              hipStream_t stream) {
    float* w = (float*)d_ws;

    static const int dictSz[18]  = {65536,262144,16384,256,65536,256,131072,256,65536,256,
                                    196608,196608,768,768,65536,256,4096,16};
    static const int alphaSz[18] = {262144,196608,196608,768,768,131072,65536,256,256,
                                    65536,16384,65536,256,256,65536,4096,256,16};
    static const int alphaPos[18] = {9,0,10,12,11,13,5,7,6,8,2,1,4,3,14,16,15,17};
    bool dictOK = true, alphaOK = true;
    for (int i = 0; i < 18 && i < n_in; ++i) {
        if (in_sizes[i] != dictSz[i])  dictOK = false;
        if (in_sizes[i] != alphaSz[i]) alphaOK = false;
    }
    MegaArgs margs;
    for (int l = 0; l < 18; ++l)
        margs.P[l] = d_in[(!dictOK && alphaOK) ? alphaPos[l] : l];
    margs.w = w;
    margs.out = d_out;

    // zero the barrier counters (workspace is poisoned between runs)
    hipMemsetAsync(w + F_BAR, 0, 4096, stream);

    void* kargs[] = { (void*)&margs };
    hipLaunchCooperativeKernel((const void*)mega_kernel, dim3(512), dim3(256),
                               kargs, 0, stream);
}

// Round 5
// 337.057 us; speedup vs baseline: 3.5468x; 1.9006x over previous
//
#include <hip/hip_runtime.h>
#include <hip/hip_bf16.h>

// B=4, N=256, F=64, H=256, A=16, T=3.  BN=1024 rows.
// bf16 inputs (runtime-verified); adjacency int32.
// GEMMs: bf16 MFMA 16x16x32. Weights are EXACT in bf16 (inputs are bf16).
// Precision: activations h/Ehat stored as split hi/lo bf16 pairs along K,
// weights duplicated along K -> A_hi@B + A_lo@B in one MFMA GEMM (~fp32 acc).
// R1: agg.gi fused via precomputed Wg = W2hat.Wih (3-term split-K, K=864).
// R2: wg_kernel latency fix. 311us, all dispatches <42us.
// R3: cooperative megakernel + cg::grid.sync -> 1195us (sync ~63us each).
// R4: hand-rolled barrier -> 640us (barrier ~26us + coop-launch ~80us).
//     Megakernel abandoned: barrier floor > kernel-boundary cost (~10us).
// R5: multi-dispatch + intra-kernel fusion (bitwise-neutral):
//     (a) wg merged into convert (block-range split)       -1 dispatch
//     (b) pre1+pre2 fused, X stays in LDS                  -1 dispatch
//     (c) gi-GEMM+GRU fused via col-triple tiles (64 blk)  -3 dispatches
//     16 -> 13 dispatches, -9MB intermediate traffic.

typedef unsigned short ushort_t;
typedef short bf8_t __attribute__((ext_vector_type(8)));
typedef float f4_t  __attribute__((ext_vector_type(4)));

#define BN_ROWS 1024

// ---- bf16 regions (USHORT offsets) ----
#define UB_NFB    0         // 65536   NF [1024][64] (exact)
#define UB_PW1T   65536     // 16384   preW1^T [256][64]
#define UB_PW2T   81920     // 65536   preW2^T [256][256]
#define UB_WCATT  147456    // 655360  Wcat^T dup [1280][512]
#define UB_WGT    802816    // 663552  Wg^T [768][864] = [hi(288)|hi(288)|lo(288)]
#define UB_H2     1728512   // 524288  h  [1024][512] hi|lo
#define UB_EHAT2  2252800   // 884736  Ehat [1024][864] hi(288)|lo(288)|hi(288)

// ---- fp32 regions (FLOAT offsets), contiguous from F_PREB1 ----
#define F_PREB1   1568768   // 256
#define F_PREB2   1569024   // 256
#define F_BCAT    1569280   // 1280  [msg_b1 | 0 | gru_bhh]
#define F_BIH     1570560   // 768
#define F_ROW1    1571328   // 65536
#define F_ROB1    1636864   // 256
#define F_ROW2    1637120   // 4096
#define F_ROB2    1641216   // 16
#define F_H       1641232   // 262144
#define F_HCAT    1903376   // 1310720 [hi_p | hj | gh]
#define F_FLAG    4000528   // 1 int

// ---- convert index space ----
#define CVa 65536     // end NFB
#define CVb 81920     // end PW1T
#define CVc 147456    // end PW2T
#define CVd 802816    // end WCATT
#define CV_TOTAL 875280   // + 72464 fp32 tail
#define NCONV 3420        // convert blocks; wg blocks follow

__device__ __forceinline__ float bf2f(ushort_t u) {
    return __uint_as_float(((unsigned int)u) << 16);
}
__device__ __forceinline__ ushort_t f2b(float v) {
    __hip_bfloat16 b = __float2bfloat16(v);
    return *reinterpret_cast<ushort_t*>(&b);
}
__device__ __forceinline__ float relu(float v) { return v < 0.f ? 0.f : v; }  // NaN-propagating
__device__ __forceinline__ float ld(const void* p, int i, int isf32) {
    return isf32 ? ((const float*)p)[i] : bf2f(((const ushort_t*)p)[i]);
}

__global__ __launch_bounds__(256) void detect_kernel(const ushort_t* __restrict__ nf,
                                                     int* __restrict__ flag) {
    __shared__ int cnt;
    if (threadIdx.x == 0) cnt = 0;
    __syncthreads();
    int bad = 0;
    for (int i = 0; i < 8; ++i) {
        ushort_t u = nf[(threadIdx.x * 8 + i) * 2];
        int ex = (u >> 7) & 0xFF;
        if ((u & 0x7fff) != 0 && (ex < 100 || ex > 140)) bad++;
    }
    atomicAdd(&cnt, bad);
    __syncthreads();
    if (threadIdx.x == 0) *flag = (cnt > 512) ? 1 : 0;
}

// convert (blocks [0,NCONV)) + wg (blocks [NCONV, NCONV+216)) in one dispatch.
__global__ __launch_bounds__(256) void convwg_kernel(
    const void* nf, const void* preW1, const void* preb1, const void* preW2, const void* preb2,
    const void* msgW1, const void* msgb1, const void* msgW2, const void* msgb2,
    const void* gruWih, const void* gruWhh, const void* grubih, const void* grubhh,
    const void* roW1, const void* rob1, const void* roW2, const void* rob2,
    float* __restrict__ w, const int* __restrict__ flagp)
{
    __shared__ float w2s[4 * 256];
    const int f32 = *flagp;
    const int t = threadIdx.x;
    ushort_t* wb = (ushort_t*)w;

    if (blockIdx.x < NCONV) {
        int e = blockIdx.x * 256 + t;
        if (e >= CV_TOTAL) return;
        if (e < CVa) {                                    // NF
            wb[UB_NFB + e] = f2b(ld(nf, e, f32));
        } else if (e < CVb) {                             // preW1^T [256][64]
            int i = e - CVa; int n = i >> 6, k = i & 63;
            wb[UB_PW1T + i] = f2b(ld(preW1, k * 256 + n, f32));
        } else if (e < CVc) {                             // preW2^T [256][256]
            int i = e - CVb; int n = i >> 8, k = i & 255;
            wb[UB_PW2T + i] = f2b(ld(preW2, k * 256 + n, f32));
        } else if (e < CVd) {                             // Wcat^T dup [1280][512]
            int i = e - CVc; int n = i >> 9, k = (i & 511) & 255;
            float v;
            if (n < 256)      v = ld(msgW1, k * 256 + n, f32);
            else if (n < 512) v = ld(msgW1, (256 + k) * 256 + (n - 256), f32);
            else              v = ld(gruWhh, k * 768 + (n - 512), f32);
            wb[UB_WCATT + i] = f2b(v);
        } else {                                          // fp32 tail (contiguous)
            int f = e - CVd;
            float v;
            if (f < 256)        v = ld(preb1, f, f32);
            else if (f < 512)   v = ld(preb2, f - 256, f32);
            else if (f < 1792) {
                int c = f - 512;
                if (c < 256)      v = ld(msgb1, c, f32);
                else if (c < 512) v = 0.f;
                else              v = ld(grubhh, c - 512, f32);
            }
            else if (f < 2560)  v = ld(grubih, f - 1792, f32);
            else if (f < 68096) v = ld(roW1, f - 2560, f32);
            else if (f < 68352) v = ld(rob1, f - 68096, f32);
            else if (f < 72448) v = ld(roW2, f - 68352, f32);
            else                v = ld(rob2, f - 72448, f32);
            w[F_PREB1 + f] = v;
        }
        return;
    }

    // ---- wg path: Wg[k][p] = sum_n W2hat[k][n]*Wih[n][p] -> WgT[p][864] ----
    const int wt = blockIdx.x - NCONV;   // [0,216)
    const int p0 = (wt % 3) * 256;
    const int k0 = (wt / 3) * 4;
    for (int i = t; i < 4 * 256; i += 256) {
        int r = i >> 8, n = i & 255;
        int krow = k0 + r;
        float v;
        if (krow < 256)       v = ld(msgW2, krow * 256 + n, f32);
        else if (krow == 256) v = ld(msgb2, n, f32);
        else                  v = 0.f;
        w2s[i] = v;
    }
    __syncthreads();
    const int p = p0 + t;
    float acc4[4] = {};
    for (int n0 = 0; n0 < 256; n0 += 32) {
        float wv[32];
#pragma unroll
        for (int i = 0; i < 32; ++i)
            wv[i] = ld(gruWih, (n0 + i) * 768 + p, f32);
#pragma unroll
        for (int r = 0; r < 4; ++r) {
            float acc = acc4[r];
#pragma unroll
            for (int q = 0; q < 8; ++q) {
                f4_t w4 = *(const f4_t*)&w2s[r * 256 + n0 + q * 4];
                acc += w4[0] * wv[q * 4 + 0] + w4[1] * wv[q * 4 + 1]
                     + w4[2] * wv[q * 4 + 2] + w4[3] * wv[q * 4 + 3];
            }
            acc4[r] = acc;
        }
    }
#pragma unroll
    for (int r = 0; r < 4; ++r) {
        int krow = k0 + r;
        ushort_t hi = f2b(acc4[r]);
        ushort_t lo = f2b(acc4[r] - bf2f(hi));
        wb[UB_WGT + p * 864 + krow] = hi;
        wb[UB_WGT + p * 864 + 288 + krow] = hi;
        wb[UB_WGT + p * 864 + 576 + krow] = lo;
    }
}

// Fused pre-net: X = relu(NF@preW1+b1) (kept in LDS), h = X@preW2+b2.
// 16 blocks x 64 rows; 4 waves, each 16 rows x 256 cols (16 n-frags).
__global__ __launch_bounds__(256) void prenet_kernel(float* __restrict__ w)
{
    __shared__ ushort_t As[64 * 64];    // NF tile
    __shared__ ushort_t Xs[64 * 256];   // X tile (bf16)
    __shared__ ushort_t Bs[256 * 32];   // weight k-slab
    ushort_t* wb = (ushort_t*)w;
    const int t = threadIdx.x;
    const int wave = t >> 6, lane = t & 63;
    const int ln = lane & 15, quad = lane >> 4;
    const int rbase = blockIdx.x * 64;
    const int srow = t >> 2, skc = (t & 3) << 3;

    // stage NF tile [64][64]
#pragma unroll
    for (int s = 0; s < 2; ++s) {
        int slot = t + 256 * s;                 // 512 slots of 8
        int row = slot >> 3, kc = (slot & 7) << 3;
        *(bf8_t*)(&As[row * 64 + kc]) =
            *(const bf8_t*)(&wb[UB_NFB + (rbase + row) * 64 + kc]);
    }

    f4_t acc[16] = {};
    // phase A: X = relu(NF @ PW1T + b1), K=64
    for (int k0 = 0; k0 < 64; k0 += 32) {
        __syncthreads();
#pragma unroll
        for (int rr = 0; rr < 4; ++rr) {
            int n = srow + 64 * rr;
            *(bf8_t*)(&Bs[n * 32 + skc]) =
                *(const bf8_t*)(&wb[UB_PW1T + n * 64 + k0 + skc]);
        }
        __syncthreads();
        bf8_t af = *(const bf8_t*)(&As[(wave * 16 + ln) * 64 + k0 + quad * 8]);
#pragma unroll
        for (int n = 0; n < 16; ++n) {
            bf8_t bfr = *(const bf8_t*)(&Bs[(n * 16 + ln) * 32 + quad * 8]);
            acc[n] = __builtin_amdgcn_mfma_f32_16x16x32_bf16(af, bfr, acc[n], 0, 0, 0);
        }
    }
    __syncthreads();
#pragma unroll
    for (int n = 0; n < 16; ++n) {
        int col = n * 16 + ln;
        float bb = w[F_PREB1 + col];
#pragma unroll
        for (int r = 0; r < 4; ++r) {
            int row = wave * 16 + quad * 4 + r;
            Xs[row * 256 + col] = f2b(relu(acc[n][r] + bb));
        }
        acc[n] = (f4_t){0.f, 0.f, 0.f, 0.f};
    }
    __syncthreads();

    // phase B: h = X @ PW2T + b2, K=256
    for (int k0 = 0; k0 < 256; k0 += 32) {
        __syncthreads();
#pragma unroll
        for (int rr = 0; rr < 4; ++rr) {
            int n = srow + 64 * rr;
            *(bf8_t*)(&Bs[n * 32 + skc]) =
                *(const bf8_t*)(&wb[UB_PW2T + n * 256 + k0 + skc]);
        }
        __syncthreads();
        bf8_t af = *(const bf8_t*)(&Xs[(wave * 16 + ln) * 256 + k0 + quad * 8]);
#pragma unroll
        for (int n = 0; n < 16; ++n) {
            bf8_t bfr = *(const bf8_t*)(&Bs[(n * 16 + ln) * 32 + quad * 8]);
            acc[n] = __builtin_amdgcn_mfma_f32_16x16x32_bf16(af, bfr, acc[n], 0, 0, 0);
        }
    }
#pragma unroll
    for (int n = 0; n < 16; ++n) {
        int col = n * 16 + ln;
        float bb = w[F_PREB2 + col];
#pragma unroll
        for (int r = 0; r < 4; ++r) {
            int grow = rbase + wave * 16 + quad * 4 + r;
            float v = acc[n][r] + bb;
            w[F_H + grow * 256 + col] = v;
            ushort_t hi = f2b(v);
            wb[UB_H2 + grow * 512 + col] = hi;
            wb[UB_H2 + grow * 512 + 256 + col] = f2b(v - bf2f(hi));
        }
    }
}

// bf16 MFMA GEMM: C[M,N] = A[M,K] @ Bt[N,K]^T (+bias).
// Block tile 64x128, 4 waves of 32x64.  (hcat GEMM)
__global__ __launch_bounds__(256) void mgemm_k(
    const ushort_t* __restrict__ A,
    const ushort_t* __restrict__ Bt,
    const float* __restrict__ bias,
    float* __restrict__ C,
    int K, int N)
{
    __shared__ ushort_t As[64 * 32];
    __shared__ ushort_t Bs[128 * 32];
    const int t = threadIdx.x;
    const int wave = t >> 6, lane = t & 63;
    const int ln = lane & 15, quad = lane >> 4;
    const int bm = blockIdx.y * 64, bn = blockIdx.x * 128;
    const int wm = (wave >> 1) * 32, wn = (wave & 1) * 64;
    const int srow = t >> 2, skc = (t & 3) << 3;

    f4_t acc[2][4] = {};

    for (int k0 = 0; k0 < K; k0 += 32) {
        __syncthreads();
        *(bf8_t*)(&As[srow * 32 + skc]) = *(const bf8_t*)(&A[(bm + srow) * K + k0 + skc]);
#pragma unroll
        for (int r = 0; r < 2; ++r) {
            int row = srow + r * 64;
            *(bf8_t*)(&Bs[row * 32 + skc]) = *(const bf8_t*)(&Bt[(bn + row) * K + k0 + skc]);
        }
        __syncthreads();
        bf8_t af[2], bfr[4];
#pragma unroll
        for (int i = 0; i < 2; ++i)
            af[i]  = *(const bf8_t*)(&As[(wm + i * 16 + ln) * 32 + quad * 8]);
#pragma unroll
        for (int i = 0; i < 4; ++i)
            bfr[i] = *(const bf8_t*)(&Bs[(wn + i * 16 + ln) * 32 + quad * 8]);
#pragma unroll
        for (int mi = 0; mi < 2; ++mi)
#pragma unroll
            for (int ni = 0; ni < 4; ++ni)
                acc[mi][ni] = __builtin_amdgcn_mfma_f32_16x16x32_bf16(
                    af[mi], bfr[ni], acc[mi][ni], 0, 0, 0);
    }

#pragma unroll
    for (int mi = 0; mi < 2; ++mi) {
#pragma unroll
        for (int ni = 0; ni < 4; ++ni) {
            int col = bn + wn + ni * 16 + ln;
            float bb = bias[col];
#pragma unroll
            for (int r = 0; r < 4; ++r) {
                int row = bm + wm + mi * 16 + quad * 4 + r;
                C[row * N + col] = acc[mi][ni][r] + bb;
            }
        }
    }
}

// Ehat[row] (width 864): [ sum relu(hi_p+hj) hi | deg | 0 | lo | 0 | hi | deg | 0 ]
__global__ __launch_bounds__(256) void msg_kernel(
    const float* __restrict__ hcat,   // [1024][1280]: [hi_p | hj | gh]
    const int*   __restrict__ adj,    // [1024][256]
    ushort_t* __restrict__ ehat)      // [1024][864]
{
    const int row = blockIdx.x;
    const int t = threadIdx.x;
    __shared__ int ej[256];
    __shared__ int ecnt;
    if (t == 0) ecnt = 0;
    __syncthreads();
    if (adj[row * 256 + t]) { int p = atomicAdd(&ecnt, 1); ej[p] = t; }
    const float hi = hcat[row * 1280 + t];
    const float* hjb = hcat + (row >> 8) * 256 * 1280 + 256;
    __syncthreads();
    const int ne = ecnt;
    float acc = 0.f;
#pragma unroll 4
    for (int p = 0; p < ne; ++p) {
        int j = ej[p];
        acc += relu(hi + hjb[j * 1280 + t]);
    }
    ushort_t h16 = f2b(acc);
    ushort_t l16 = f2b(acc - bf2f(h16));
    ushort_t* er = ehat + row * 864;
    er[t] = h16;
    er[288 + t] = l16;
    er[576 + t] = h16;
    if (t < 32) {
        ushort_t d = f2b(t == 0 ? (float)ne : 0.f);  // deg exact (<=256)
        er[256 + t] = d;
        er[544 + t] = 0;
        er[832 + t] = d;
    }
}

// Fused gi-GEMM + GRU: block = 64 rows x col-triple {cg*64.., 256+.., 512+..}.
// gi = Ehat @ Wg + bih (K=864); GRU runs in epilogue from registers.
// Grid 64 = 16 row-groups x 4 col-groups. Wave = 16 rows x 12 n-frags.
__global__ __launch_bounds__(256) void gigru_kernel(float* __restrict__ w)
{
    __shared__ ushort_t As[64 * 32];
    __shared__ ushort_t Bs[192 * 32];
    ushort_t* wb = (ushort_t*)w;
    const int t = threadIdx.x;
    const int wave = t >> 6, lane = t & 63;
    const int ln = lane & 15, quad = lane >> 4;
    const int rg = blockIdx.x >> 2, cg = blockIdx.x & 3;
    const int rbase = rg * 64;
    const int srow = t >> 2, skc = (t & 3) << 3;

    f4_t acc[12] = {};

    for (int k0 = 0; k0 < 864; k0 += 32) {
        __syncthreads();
        *(bf8_t*)(&As[srow * 32 + skc]) =
            *(const bf8_t*)(&wb[UB_EHAT2 + (rbase + srow) * 864 + k0 + skc]);
#pragma unroll
        for (int rr = 0; rr < 3; ++rr) {
            int br = srow + 64 * rr;                       // [0,192)
            int wrow = (br >> 6) * 256 + cg * 64 + (br & 63);
            *(bf8_t*)(&Bs[br * 32 + skc]) =
                *(const bf8_t*)(&wb[UB_WGT + wrow * 864 + k0 + skc]);
        }
        __syncthreads();
        bf8_t af = *(const bf8_t*)(&As[(wave * 16 + ln) * 32 + quad * 8]);
#pragma unroll
        for (int n = 0; n < 12; ++n) {
            bf8_t bfr = *(const bf8_t*)(&Bs[(n * 16 + ln) * 32 + quad * 8]);
            acc[n] = __builtin_amdgcn_mfma_f32_16x16x32_bf16(af, bfr, acc[n], 0, 0, 0);
        }
    }

    // GRU epilogue: n 0..3 = ir cols, 4..7 = iz, 8..11 = in (same col triple).
#pragma unroll
    for (int n = 0; n < 4; ++n) {
        int col = cg * 64 + n * 16 + ln;
        float bi_r = w[F_BIH + col];
        float bi_z = w[F_BIH + 256 + col];
        float bi_n = w[F_BIH + 512 + col];
#pragma unroll
        for (int r = 0; r < 4; ++r) {
            int row = rbase + wave * 16 + quad * 4 + r;
            float ir = acc[n][r] + bi_r;
            float iz = acc[n + 4][r] + bi_z;
            float in = acc[n + 8][r] + bi_n;
            const float* ghr = w + F_HCAT + row * 1280 + 512;
            float hr = ghr[col], hz = ghr[256 + col], hn = ghr[512 + col];
            float rg_ = 1.f / (1.f + __expf(-(ir + hr)));
            float z   = 1.f / (1.f + __expf(-(iz + hz)));
            float nn  = tanhf(in + rg_ * hn);
            float ho = w[F_H + row * 256 + col];
            float hv = (1.f - z) * nn + z * ho;
            w[F_H + row * 256 + col] = hv;
            ushort_t hb = f2b(hv);
            wb[UB_H2 + row * 512 + col] = hb;
            wb[UB_H2 + row * 512 + 256 + col] = f2b(hv - bf2f(hb));
        }
    }
}

__global__ __launch_bounds__(256) void readout_kernel(
    const float* __restrict__ h,
    const float* __restrict__ roW1, const float* __restrict__ rob1,
    const float* __restrict__ roW2, const float* __restrict__ rob2,
    void* __restrict__ out, const int* __restrict__ flagp)
{
    const int b = blockIdx.x;
    const int t = threadIdx.x;
    __shared__ float gl[256], t1[256];
    const float* hb = h + b * 256 * 256;
    float s = 0.f;
    for (int n = 0; n < 256; ++n) s += hb[n * 256 + t];
    gl[t] = s;
    __syncthreads();
    float acc = rob1[t];
    for (int k = 0; k < 256; ++k) acc += gl[k] * roW1[k * 256 + t];
    t1[t] = relu(acc);
    __syncthreads();
    if (t < 16) {
        float q = rob2[t];
        for (int k = 0; k < 256; ++k) q += t1[k] * roW2[k * 16 + t];
        if (*flagp) ((float*)out)[b * 16 + t] = q;
        else ((__hip_bfloat16*)out)[b * 16 + t] = __float2bfloat16(q);
    }
}

extern "C" void kernel_launch(void* const* d_in, const int* in_sizes, int n_in,
                              void* d_out, int out_size, void* d_ws, size_t ws_size,
                              hipStream_t stream) {
    float* w = (float*)d_ws;
    ushort_t* wb = (ushort_t*)d_ws;
    int* flagp = (int*)(w + F_FLAG);

    static const int dictSz[18]  = {65536,262144,16384,256,65536,256,131072,256,65536,256,
                                    196608,196608,768,768,65536,256,4096,16};
    static const int alphaSz[18] = {262144,196608,196608,768,768,131072,65536,256,256,
                                    65536,16384,65536,256,256,65536,4096,256,16};
    static const int alphaPos[18] = {9,0,10,12,11,13,5,7,6,8,2,1,4,3,14,16,15,17};
    bool dictOK = true, alphaOK = true;
    for (int i = 0; i < 18 && i < n_in; ++i) {
        if (in_sizes[i] != dictSz[i])  dictOK = false;
        if (in_sizes[i] != alphaSz[i]) alphaOK = false;
    }
    const void* P[18];
    for (int l = 0; l < 18; ++l) P[l] = d_in[(!dictOK && alphaOK) ? alphaPos[l] : l];
    const int* adj = (const int*)P[1];

    detect_kernel<<<1, 256, 0, stream>>>((const ushort_t*)P[0], flagp);
    convwg_kernel<<<NCONV + 216, 256, 0, stream>>>(
        P[0], P[2], P[3], P[4], P[5], P[6], P[7], P[8], P[9],
        P[10], P[11], P[12], P[13], P[14], P[15], P[16], P[17], w, flagp);

    // fused pre-net: X in LDS; writes F_H + UB_H2
    prenet_kernel<<<16, 256, 0, stream>>>(w);

    for (int it = 0; it < 3; ++it) {
        // hcat = h @ [W1_i|W1_j|Whh] + [b1|0|bhh]   (A = h hi|lo, K=512)
        mgemm_k<<<dim3(10, 16), 256, 0, stream>>>(
            wb + UB_H2, wb + UB_WCATT, w + F_BCAT, w + F_HCAT, 512, 1280);
        msg_kernel<<<BN_ROWS, 256, 0, stream>>>(w + F_HCAT, adj, wb + UB_EHAT2);
        // fused gi+GRU: gi = Ehat @ Wg + bih (K=864), GRU in epilogue
        gigru_kernel<<<64, 256, 0, stream>>>(w);
    }

    readout_kernel<<<4, 256, 0, stream>>>(w + F_H, w + F_ROW1, w + F_ROB1,
                                          w + F_ROW2, w + F_ROB2, d_out, flagp);
}